// Round 6
// baseline (175.592 us; speedup 1.0000x reference)
//
#include <hip/hip_runtime.h>

// Causal GQA attention: S=2048, H=32, KVH=8, D=128, fp32 in/out.
// R6 = R5 + (a) conflict-free K swizzle v2 (R5's c^(key&7) left a 4-way
// conflict on K-frag b128 reads -- bit-identical SQ_LDS_BANK_CONFLICT in
// R4/R5 was the tell); (b) equal-duration co-residency: co-resident blocks
// (b, b+256) now have adjacent qt durations so critical CUs stay 2-deep for
// the whole makespan; (c) merged pre-pass (1 launch). Core structure (DMA
// staging, S^T operand swap, 16x16x16 PV with pk-as-B-frag, no-max softmax)
// unchanged from the verified R5.

#define SEQ   2048
#define NH    32
#define NKV   8
#define HD    128
#define QLD   4096      // NH*HD
#define KLD   1024      // NKV*HD
#define VT_HEAD (HD * SEQ)   // elems per kv-head in V^T

typedef __attribute__((ext_vector_type(8))) __bf16 bf16x8;
typedef __attribute__((ext_vector_type(4))) __bf16 bf16x4;
typedef __attribute__((ext_vector_type(2))) __bf16 bf16x2;
typedef __attribute__((ext_vector_type(4))) float  f32x4;
typedef __attribute__((ext_vector_type(4))) short  s16x4;
typedef __attribute__((ext_vector_type(2))) unsigned int u32x2;

static __device__ __forceinline__ unsigned int pack2(float lo, float hi) {
  bf16x2 t; t[0] = (__bf16)lo; t[1] = (__bf16)hi;
  return __builtin_bit_cast(unsigned int, t);
}

// K LDS swizzle: granule(key, c) = key*16 + (c ^ gk(key&15)),
// gk = (key&3) | (((key>>1)&3) << 2). For fixed ch the frag-read bank column
// (16*(l15&1) + (4ch+quad)^gk(l15)) is bijective in (l15[2:0], quad) -> 32
// distinct columns, 2-way via l15[3] (free).
static __device__ __forceinline__ int gk_sw(int key) {
  return (key & 3) | (((key >> 1) & 3) << 2);
}

static __device__ __forceinline__ f32x4 mfma16(bf16x4 a, u32x2 b, f32x4 c) {
#if __has_builtin(__builtin_amdgcn_mfma_f32_16x16x16bf16_1k)
  return __builtin_amdgcn_mfma_f32_16x16x16bf16_1k(
      __builtin_bit_cast(s16x4, a), __builtin_bit_cast(s16x4, b), c, 0, 0, 0);
#else
  asm volatile("v_mfma_f32_16x16x16_bf16 %0, %1, %2, %0"
               : "+v"(c) : "v"(a), "v"(b));
  return c;
#endif
}

// ---- merged pre-pass: K fp32->bf16 (blocks 0..2047); V -> V^T bf16 (rest) ----
__global__ void prepass(const float* __restrict__ k, const float* __restrict__ v,
                        __bf16* __restrict__ kb, __bf16* __restrict__ vt) {
  if (blockIdx.x < 2048) {
    const int i = (blockIdx.x * 256 + threadIdx.x) * 4;
    float4 x = *(const float4*)(k + i);
    bf16x4 b;
    b[0] = (__bf16)x.x; b[1] = (__bf16)x.y; b[2] = (__bf16)x.z; b[3] = (__bf16)x.w;
    *(bf16x4*)(kb + i) = b;
    return;
  }
  __shared__ __bf16 TT[HD][72];
  const int vb  = blockIdx.x - 2048;     // 0..255
  const int kvh = vb >> 5;
  const int kbse = (vb & 31) * 64;
  const int t   = threadIdx.x;
  {
    const int key = t >> 2, dq = t & 3;
    const float* vp = v + (size_t)(kbse + key) * KLD + kvh * HD + dq * 32;
#pragma unroll
    for (int j = 0; j < 8; ++j) {
      float4 x = *(const float4*)(vp + j * 4);
      const int d = dq * 32 + j * 4;
      TT[d + 0][key] = (__bf16)x.x; TT[d + 1][key] = (__bf16)x.y;
      TT[d + 2][key] = (__bf16)x.z; TT[d + 3][key] = (__bf16)x.w;
    }
  }
  __syncthreads();
  {
    const int dim = t >> 1, kh = (t & 1) * 32;
    __bf16* op = vt + (size_t)kvh * VT_HEAD + (size_t)dim * SEQ + kbse + kh;
#pragma unroll
    for (int j = 0; j < 8; ++j)
      *(bf16x4*)(op + j * 4) = *(const bf16x4*)&TT[dim][kh + j * 4];
  }
}

// ---- main kernel ----
__global__ __launch_bounds__(256, 2)
void fa_kernel(const float* __restrict__ q, const __bf16* __restrict__ kg,
               const __bf16* __restrict__ vt, float* __restrict__ out) {
  __shared__ __bf16 KB[2][8192];   // 2 x 16 KB, swizzled v2
  __shared__ __bf16 VB[2][8192];   // 2 x 16 KB, R5 layout (conflict-free)

  const int head = blockIdx.x;
  const int yb   = blockIdx.y;
  // adjacent-duration pairing: co-resident (yb, yb+8) -> qt (15-2i, 14-2i)
  const int qt   = (yb < 8) ? (15 - 2 * yb) : (14 - 2 * (yb - 8));
  const int kvh  = head >> 2;
  const int tid  = threadIdx.x;
  const int wave = tid >> 6;
  const int lane = tid & 63;
  const int l15  = lane & 15;
  const int quad = lane >> 4;
  const int h3   = l15 & 7;
  const int rw   = qt * 128 + wave * 32;

  constexpr float QS = 0.08838834764831845f * 1.4426950408889634f; // scale*log2e

  // Q fragments (B-operand of S^T = K*Q^T): B[k=quad*8+j][n=l15]
  bf16x8 qf[2][4];
#pragma unroll
  for (int sub = 0; sub < 2; ++sub) {
    const float* qp = q + (size_t)(rw + sub * 16 + l15) * QLD + head * HD + quad * 8;
#pragma unroll
    for (int c = 0; c < 4; ++c) {
      float4 a0 = *(const float4*)(qp + c * 32);
      float4 a1 = *(const float4*)(qp + c * 32 + 4);
      bf16x8 f;
      f[0] = (__bf16)(a0.x * QS); f[1] = (__bf16)(a0.y * QS);
      f[2] = (__bf16)(a0.z * QS); f[3] = (__bf16)(a0.w * QS);
      f[4] = (__bf16)(a1.x * QS); f[5] = (__bf16)(a1.y * QS);
      f[6] = (__bf16)(a1.z * QS); f[7] = (__bf16)(a1.w * QS);
      qf[sub][c] = f;
    }
  }

  // DMA lane->global offsets (elements)
  int kgo[4], vgo[4];
#pragma unroll
  for (int j = 0; j < 4; ++j) {
    const int key = (wave * 4 + j) * 4 + (lane >> 4);
    const int c   = (lane & 15) ^ gk_sw(key & 15);
    kgo[j] = key * KLD + kvh * HD + c * 8;
    const int dim = (wave * 4 + j) * 8 + (lane >> 3);
    const int kc  = (lane & 7) ^ (dim & 7);
    vgo[j] = kvh * VT_HEAD + dim * SEQ + kc * 8;
  }

  auto dma_tile = [&](int kbase, int buf) {
#pragma unroll
    for (int j = 0; j < 4; ++j)
      __builtin_amdgcn_global_load_lds(
          (const __attribute__((address_space(1))) unsigned int*)(kg + kbase * KLD + kgo[j]),
          (__attribute__((address_space(3))) unsigned int*)&KB[buf][(wave * 4 + j) * 512],
          16, 0, 0);
#pragma unroll
    for (int j = 0; j < 4; ++j)
      __builtin_amdgcn_global_load_lds(
          (const __attribute__((address_space(1))) unsigned int*)(vt + kbase + vgo[j]),
          (__attribute__((address_space(3))) unsigned int*)&VB[buf][(wave * 4 + j) * 512],
          16, 0, 0);
  };

  // fragment byte offsets (conflict-free by construction)
  const int gkl = gk_sw(l15);
  int kaddr[4], vaddr[4];
#pragma unroll
  for (int c = 0; c < 4; ++c)
    kaddr[c] = l15 * 256 + (((c * 4 + quad) ^ gkl) * 16);
#pragma unroll
  for (int kt = 0; kt < 4; ++kt)
    vaddr[kt] = l15 * 128 + (((kt * 2 + (quad >> 1)) ^ h3) * 16) + (quad & 1) * 8;

  f32x4 acc[2][8];
  f32x4 lp[2];
#pragma unroll
  for (int sub = 0; sub < 2; ++sub) {
    lp[sub] = (f32x4){0.f, 0.f, 0.f, 0.f};
#pragma unroll
    for (int nt = 0; nt < 8; ++nt) acc[sub][nt] = (f32x4){0.f, 0.f, 0.f, 0.f};
  }

  const int ntiles = 2 * qt + 2;
  dma_tile(0, 0);
  __syncthreads();   // barrier implies vmcnt(0): tile 0 staged

  for (int t = 0; t < ntiles; ++t) {
    const int buf = t & 1;
    if (t + 1 < ntiles) dma_tile((t + 1) * 64, buf ^ 1);  // overlaps compute

    const char* Kb = (const char*)&KB[buf][0];
    const char* Vb = (const char*)&VB[buf][0];

    // ---- S^T = K*Q^T (C-layout: key = quad*4+e, qrow = l15), then exp2 ----
    u32x2 pk[2][4];
#pragma unroll
    for (int nt = 0; nt < 4; ++nt) {
      bf16x8 kf[4];
#pragma unroll
      for (int c = 0; c < 4; ++c)
        kf[c] = *(const bf16x8*)(Kb + kaddr[c] + nt * 4096);
#pragma unroll
      for (int sub = 0; sub < 2; ++sub) {
        f32x4 s = (f32x4){0.f, 0.f, 0.f, 0.f};
#pragma unroll
        for (int c = 0; c < 4; ++c)
          s = __builtin_amdgcn_mfma_f32_16x16x32_bf16(kf[c], qf[sub][c], s, 0, 0, 0);
        if (t * 64 + 63 > rw + sub * 16) {        // causal mask (wave-uniform)
          const int key0  = t * 64 + nt * 16 + quad * 4;
          const int myrow = rw + sub * 16 + l15;
#pragma unroll
          for (int e = 0; e < 4; ++e)
            if (key0 + e > myrow) s[e] = -1e30f;
        }
        f32x4 p;
#pragma unroll
        for (int e = 0; e < 4; ++e) p[e] = __builtin_amdgcn_exp2f(s[e]);
        lp[sub] += p;
        u32x2 pkk;
        pkk.x = pack2(p[0], p[1]);
        pkk.y = pack2(p[2], p[3]);
        pk[sub][nt] = pkk;
      }
    }

    // ---- O^T += V^T * P  (16x16x16: B-frag = pk as-is, zero shuffles) ----
#pragma unroll
    for (int kt = 0; kt < 4; ++kt) {
#pragma unroll
      for (int nt = 0; nt < 8; ++nt) {
        bf16x4 vf = *(const bf16x4*)(Vb + vaddr[kt] + nt * 2048);
#pragma unroll
        for (int sub = 0; sub < 2; ++sub)
          acc[sub][nt] = mfma16(vf, pk[sub][kt], acc[sub][nt]);
      }
    }
    __syncthreads();   // drains next tile's DMA; frees buf for t+2
  }

  // ---- epilogue ----
#pragma unroll
  for (int sub = 0; sub < 2; ++sub) {
    float ls = lp[sub][0] + lp[sub][1] + lp[sub][2] + lp[sub][3];
    ls += __shfl_xor(ls, 16);
    ls += __shfl_xor(ls, 32);
    const float inv = 1.0f / ls;
    float* op = out + (size_t)(rw + sub * 16 + l15) * QLD + head * HD + quad * 4;
#pragma unroll
    for (int nt = 0; nt < 8; ++nt) {
      f32x4 r = acc[sub][nt];
      float4 w = {r[0] * inv, r[1] * inv, r[2] * inv, r[3] * inv};
      *(float4*)(op + nt * 16) = w;
    }
  }
}

extern "C" void kernel_launch(void* const* d_in, const int* in_sizes, int n_in,
                              void* d_out, int out_size, void* d_ws, size_t ws_size,
                              hipStream_t stream) {
  const float* q = (const float*)d_in[0];
  const float* k = (const float*)d_in[1];
  const float* v = (const float*)d_in[2];
  float* o = (float*)d_out;
  __bf16* kbf = (__bf16*)d_ws;                     // 4 MB: K bf16
  __bf16* vtb = (__bf16*)d_ws + (size_t)SEQ * KLD; // 4 MB: V^T bf16
  prepass<<<2048 + 256, 256, 0, stream>>>(k, v, kbf, vtb);
  fa_kernel<<<dim3(32, 16), 256, 0, stream>>>(q, kbf, vtb, o);
}